// Round 17
// baseline (230.351 us; speedup 1.0000x reference)
//
#include <hip/hip_runtime.h>
#include <hip/hip_fp16.h>
#include <hip/hip_fp8.h>

#define N_NODES 100000
#define E_EDGES 3200000
#define F_IN 11
#define F_H 64
#define F_E 32

#define BUCKETS ((N_NODES + 255) >> 8)   // 391 coarse buckets (dst>>8)
#define CAP 9216                         // slack bucket capacity (mean ~8184, +11 sigma)
#define CHUNK_A 12288
#define NWG_A ((E_EDGES + CHUNK_A - 1) / CHUNK_A)  // 261
#define EPT 12                           // binA edges per thread (CHUNK_A / 1024)
#define EPT_B ((CAP + 511) / 512)        // binB pairs per thread (18)

typedef __attribute__((ext_vector_type(8))) _Float16 f16x8;
typedef __attribute__((ext_vector_type(4))) float f32x4;

// ---------------- binA: LDS counting-sort -> coalesced global pair writes ----------
__global__ void binA_kernel(const int* __restrict__ src,
                            const int* __restrict__ dst,
                            int* __restrict__ cursor,
                            unsigned int* __restrict__ pairs) {
    __shared__ int lh[BUCKETS + 1];
    __shared__ int lstart[BUCKETS + 1];
    __shared__ int lcur[BUCKETS];
    __shared__ int gbase[BUCKETS];
    __shared__ unsigned int stage[CHUNK_A];
    int t = threadIdx.x;
    for (int i = t; i <= BUCKETS; i += 1024) lh[i] = 0;
    __syncthreads();

    int e0 = blockIdx.x * CHUNK_A;
    int e1 = min(e0 + CHUNK_A, E_EDGES);

    unsigned int pv[EPT];
    int pb[EPT];
    int cnt = 0;
    for (int i = e0 + t; i < e1; i += 1024) {
        int d = dst[i];
        int b = d >> 8;
        pv[cnt] = (unsigned int)src[i] | (((unsigned int)(d & 255)) << 17);
        pb[cnt] = b;
        ++cnt;
        atomicAdd(&lh[b], 1);
    }
    __syncthreads();

    for (int i = t; i < BUCKETS; i += 1024) lstart[i] = lh[i];
    __syncthreads();
    for (int off = 1; off < 512; off <<= 1) {
        int v = 0;
        if (t < BUCKETS && t >= off) v = lstart[t - off];
        __syncthreads();
        if (t < BUCKETS && t >= off) lstart[t] += v;
        __syncthreads();
    }
    int myIncl = (t < BUCKETS) ? lstart[t] : 0;
    int myCnt  = (t < BUCKETS) ? lh[t] : 0;
    __syncthreads();
    if (t < BUCKETS) {
        int ex = myIncl - myCnt;
        lstart[t] = ex;
        lcur[t] = ex;
        if (myCnt > 0) gbase[t] = t * CAP + atomicAdd(&cursor[t], myCnt);
    }
    if (t == 0) lstart[BUCKETS] = e1 - e0;
    __syncthreads();

    for (int k = 0; k < cnt; ++k) {
        int pos = atomicAdd(&lcur[pb[k]], 1);
        stage[pos] = pv[k];
    }
    __syncthreads();

    int total = e1 - e0;
    for (int i = t; i < total; i += 1024) {
        int lo = 0, hi = BUCKETS;
        while (hi - lo > 1) {
            int mid = (lo + hi) >> 1;
            if (lstart[mid] <= i) lo = mid; else hi = mid;
        }
        pairs[gbase[lo] + (i - lstart[lo])] = stage[i];
    }
}

// ---------------- binB: single pairs read, LDS sort, coalesced csr write ----------
__global__ __launch_bounds__(512) void binB_kernel(const unsigned int* __restrict__ pairs,
                                                   const int* __restrict__ cursor,
                                                   int* __restrict__ deg_i,
                                                   int* __restrict__ offsets,
                                                   int* __restrict__ csr_src) {
    __shared__ int lhist[256];
    __shared__ int lscan[256];
    __shared__ int lcur[256];
    __shared__ unsigned int stage[CAP];
    int b = blockIdx.x;
    int t = threadIdx.x;
    if (t < 256) lhist[t] = 0;
    __syncthreads();
    int start = b * CAP;
    int cntAll = cursor[b];
    unsigned int pv[EPT_B];
    int c = 0;
    for (int i = t; i < cntAll; i += 512) {
        unsigned int p = pairs[start + i];
        pv[c++] = p;
        atomicAdd(&lhist[p >> 17], 1);
    }
    __syncthreads();
    int cnt = (t < 256) ? lhist[t] : 0;
    if (t < 256) lscan[t] = cnt;
    __syncthreads();
    int incl = cnt;
    for (int off = 1; off < 256; off <<= 1) {
        int tmp = (t < 256 && t >= off) ? lscan[t - off] : 0;
        __syncthreads();
        if (t < 256) {
            incl += tmp;
            lscan[t] = incl;
        }
        __syncthreads();
    }
    if (t < 256) {
        int ex = incl - cnt;
        int node = (b << 8) + t;
        if (node < N_NODES) {
            deg_i[node] = cnt;
            offsets[node] = start + ex;
        }
        lcur[t] = ex;
    }
    __syncthreads();
    for (int k = 0; k < c; ++k) {
        int pos = atomicAdd(&lcur[pv[k] >> 17], 1);
        stage[pos] = pv[k] & 0x1FFFFu;
    }
    __syncthreads();
    for (int i = t; i < cntAll; i += 512)
        csr_src[start + i] = (int)stage[i];
}

// ---------------- fp16 conversion of x: [N][12] halves (24B rows) ----------------
__global__ void convert_x_kernel(const float* __restrict__ x, __half* __restrict__ xh) {
    int tid = blockIdx.x * blockDim.x + threadIdx.x;
    if (tid >= N_NODES * 12) return;
    int n = tid / 12;
    int f = tid - n * 12;
    xh[tid] = __float2half((f < F_IN) ? x[n * F_IN + f] : 0.0f);
}

// ---------------- layer 1 gather: 32 lanes/node (8 feat-lanes x 4 deg-quarters) -----
__global__ void gather1_kernel(const int* __restrict__ csr_src,
                               const int* __restrict__ offsets,
                               const int* __restrict__ deg_i,
                               const __half2* __restrict__ xh2,
                               float* __restrict__ agg1) {
    int tid = blockIdx.x * blockDim.x + threadIdx.x;
    int n = tid >> 5;
    int lane32 = tid & 31;
    int f2 = lane32 & 7;
    int q = lane32 >> 3;
    if (n >= N_NODES) return;
    int start = offsets[n];
    int cnt = deg_i[n];
    int i0 = start + ((cnt * q) >> 2);
    int i1 = start + ((cnt * (q + 1)) >> 2);
    float2 r = {0.f, 0.f};
    if (f2 < 6) {
        float2 a0 = {0,0}, a1 = {0,0}, a2 = {0,0}, a3 = {0,0};
        int i = i0;
        for (; i + 4 <= i1; i += 4) {
            int s0 = csr_src[i], s1 = csr_src[i + 1], s2 = csr_src[i + 2], s3 = csr_src[i + 3];
            float2 v0 = __half22float2(xh2[s0 * 6 + f2]);
            float2 v1 = __half22float2(xh2[s1 * 6 + f2]);
            float2 v2 = __half22float2(xh2[s2 * 6 + f2]);
            float2 v3 = __half22float2(xh2[s3 * 6 + f2]);
            a0.x += v0.x; a0.y += v0.y;
            a1.x += v1.x; a1.y += v1.y;
            a2.x += v2.x; a2.y += v2.y;
            a3.x += v3.x; a3.y += v3.y;
        }
        for (; i < i1; ++i) {
            float2 v = __half22float2(xh2[csr_src[i] * 6 + f2]);
            a0.x += v.x; a0.y += v.y;
        }
        r.x = a0.x + a1.x + a2.x + a3.x;
        r.y = a0.y + a1.y + a2.y + a3.y;
    }
    r.x += __shfl_xor(r.x, 8);
    r.y += __shfl_xor(r.y, 8);
    r.x += __shfl_xor(r.x, 16);
    r.y += __shfl_xor(r.y, 16);
    if (q == 0 && f2 < 6)
        ((float2*)agg1)[n * 6 + f2] = r;
}

// ---------------- fused layer1 + dual projection via MFMA ----------------
__global__ __launch_bounds__(256) void layer1_proj_kernel(
        const float* __restrict__ x,
        const float* __restrict__ agg1,
        const int* __restrict__ deg_i,
        const float* __restrict__ W1l,
        const float* __restrict__ W1r,
        const float* __restrict__ b1,
        const float* __restrict__ W2l,
        const float* __restrict__ W2r,
        const float* __restrict__ b2,
        unsigned char* __restrict__ p8,
        float* __restrict__ r2) {
    __shared__ __attribute__((aligned(16))) _Float16 hA1[64][32];
    __shared__ __attribute__((aligned(16))) _Float16 WB1[64][32];
    __shared__ __attribute__((aligned(16))) _Float16 WB2[64][64];
    __shared__ __attribute__((aligned(16))) _Float16 hS[64][64];
    int t = threadIdx.x;
    int n0 = blockIdx.x * 64;

    for (int i = t; i < 64 * 32; i += 256) {
        int n = i >> 5, k = i & 31;
        float v = 0.0f;
        if (k < F_IN) v = W1l[k * F_H + n];
        else if (k < 2 * F_IN) v = W1r[(k - F_IN) * F_H + n];
        WB1[n][k] = (_Float16)v;
    }
    for (int i = t; i < 64 * 64; i += 256) {
        int n = i >> 6, k = i & 63;
        float v = (n < F_E) ? W2l[k * F_E + n] : W2r[k * F_E + (n - F_E)];
        WB2[n][k] = (_Float16)v;
    }
    for (int i = t; i < 64 * 32; i += 256) {
        int nl = i >> 5, k = i & 31;
        int n = n0 + nl;
        if (n >= N_NODES) n = N_NODES - 1;
        float v = 0.0f;
        if (k < F_IN) {
            float invd = 1.0f / fmaxf((float)deg_i[n], 1.0f);
            v = agg1[n * 12 + k] * invd;
        } else if (k < 2 * F_IN) {
            v = x[n * F_IN + (k - F_IN)];
        }
        hA1[nl][k] = (_Float16)v;
    }
    __syncthreads();

    int lane = t & 63;
    int wave = t >> 6;
    int col = lane & 15;
    int quad = lane >> 4;
    int mbase = wave * 16;

    f16x8 afrag = *(const f16x8*)&hA1[mbase + col][quad * 8];
    #pragma unroll
    for (int nt = 0; nt < 4; ++nt) {
        f16x8 bfrag = *(const f16x8*)&WB1[nt * 16 + col][quad * 8];
        float bias = b1[nt * 16 + col];
        f32x4 acc = {bias, bias, bias, bias};
        acc = __builtin_amdgcn_mfma_f32_16x16x32_f16(afrag, bfrag, acc, 0, 0, 0);
        #pragma unroll
        for (int r = 0; r < 4; ++r)
            hS[mbase + quad * 4 + r][nt * 16 + col] = (_Float16)fmaxf(acc[r], 0.0f);
    }
    __syncthreads();

    f16x8 a0 = *(const f16x8*)&hS[mbase + col][quad * 8];
    f16x8 a1 = *(const f16x8*)&hS[mbase + col][32 + quad * 8];
    #pragma unroll
    for (int nt = 0; nt < 4; ++nt) {
        f16x8 bf0 = *(const f16x8*)&WB2[nt * 16 + col][quad * 8];
        f16x8 bf1 = *(const f16x8*)&WB2[nt * 16 + col][32 + quad * 8];
        f32x4 acc;
        if (nt < 2) {
            acc = (f32x4){0.f, 0.f, 0.f, 0.f};
        } else {
            float bb = b2[(nt - 2) * 16 + col];
            acc = (f32x4){bb, bb, bb, bb};
        }
        acc = __builtin_amdgcn_mfma_f32_16x16x32_f16(a0, bf0, acc, 0, 0, 0);
        acc = __builtin_amdgcn_mfma_f32_16x16x32_f16(a1, bf1, acc, 0, 0, 0);
        #pragma unroll
        for (int r = 0; r < 4; ++r) {
            int node = n0 + mbase + quad * 4 + r;
            if (node < N_NODES) {
                if (nt < 2) {
                    __hip_fp8_e4m3 q((float)acc[r]);
                    p8[(size_t)node * F_E + nt * 16 + col] = (unsigned char)q.__x;
                } else {
                    r2[(size_t)node * F_E + (nt - 2) * 16 + col] = acc[r];
                }
            }
        }
    }
}

// decode 4 packed fp8 e4m3 -> 4 floats
__device__ inline float4 fp8x4_to_f32(unsigned int w) {
    __hip_fp8_e4m3 a, b, c, d;
    a.__x = (__hip_fp8_storage_t)(w & 0xFF);
    b.__x = (__hip_fp8_storage_t)((w >> 8) & 0xFF);
    c.__x = (__hip_fp8_storage_t)((w >> 16) & 0xFF);
    d.__x = (__hip_fp8_storage_t)((w >> 24) & 0xFF);
    return make_float4((float)a, (float)b, (float)c, (float)d);
}

// ---------------- layer 2 fused: 32 lanes/node (8 feat-lanes x 4 deg-quarters) ------
__global__ void layer2_fused_kernel(const int* __restrict__ csr_src,
                                    const int* __restrict__ offsets,
                                    const int* __restrict__ deg_i,
                                    const unsigned int* __restrict__ p8u,  // [N][8] uint
                                    const float* __restrict__ r2,
                                    const float* __restrict__ Wc,
                                    const float* __restrict__ bc,
                                    float* __restrict__ emb,
                                    float* __restrict__ logits) {
    int tid = blockIdx.x * blockDim.x + threadIdx.x;
    int n = tid >> 5;
    int lane32 = tid & 31;
    int l = lane32 & 7;
    int q = lane32 >> 3;
    if (n >= N_NODES) return;
    int start = offsets[n];
    int cnt = deg_i[n];
    int i0 = start + ((cnt * q) >> 2);
    int i1 = start + ((cnt * (q + 1)) >> 2);
    float ax = 0.f, ay = 0.f, az = 0.f, aw = 0.f;
    float bx = 0.f, by = 0.f, bz = 0.f, bw = 0.f;
    int i = i0;
    for (; i + 4 <= i1; i += 4) {
        int s0 = csr_src[i], s1 = csr_src[i + 1], s2 = csr_src[i + 2], s3 = csr_src[i + 3];
        unsigned int w0 = p8u[s0 * 8 + l];
        unsigned int w1 = p8u[s1 * 8 + l];
        unsigned int w2 = p8u[s2 * 8 + l];
        unsigned int w3 = p8u[s3 * 8 + l];
        float4 v0 = fp8x4_to_f32(w0);
        float4 v1 = fp8x4_to_f32(w1);
        float4 v2 = fp8x4_to_f32(w2);
        float4 v3 = fp8x4_to_f32(w3);
        ax += v0.x + v2.x; ay += v0.y + v2.y; az += v0.z + v2.z; aw += v0.w + v2.w;
        bx += v1.x + v3.x; by += v1.y + v3.y; bz += v1.z + v3.z; bw += v1.w + v3.w;
    }
    for (; i < i1; ++i) {
        float4 v = fp8x4_to_f32(p8u[csr_src[i] * 8 + l]);
        ax += v.x; ay += v.y; az += v.z; aw += v.w;
    }
    float sx = ax + bx, sy = ay + by, sz = az + bz, sw = aw + bw;
    sx += __shfl_xor(sx, 8);
    sy += __shfl_xor(sy, 8);
    sz += __shfl_xor(sz, 8);
    sw += __shfl_xor(sw, 8);
    sx += __shfl_xor(sx, 16);
    sy += __shfl_xor(sy, 16);
    sz += __shfl_xor(sz, 16);
    sw += __shfl_xor(sw, 16);
    if (q != 0) return;
    float invd = 1.0f / fmaxf((float)cnt, 1.0f);
    const float* rrow = r2 + n * F_E + 4 * l;
    float4 e;
    e.x = fmaxf(sx * invd + rrow[0], 0.0f);
    e.y = fmaxf(sy * invd + rrow[1], 0.0f);
    e.z = fmaxf(sz * invd + rrow[2], 0.0f);
    e.w = fmaxf(sw * invd + rrow[3], 0.0f);
    ((float4*)emb)[n * 8 + l] = e;
    const float* wc = Wc + (4 * l) * 3;
    float c0 = e.x * wc[0] + e.y * wc[3] + e.z * wc[6] + e.w * wc[9];
    float c1 = e.x * wc[1] + e.y * wc[4] + e.z * wc[7] + e.w * wc[10];
    float c2 = e.x * wc[2] + e.y * wc[5] + e.z * wc[8] + e.w * wc[11];
    #pragma unroll
    for (int m = 1; m < 8; m <<= 1) {
        c0 += __shfl_xor(c0, m);
        c1 += __shfl_xor(c1, m);
        c2 += __shfl_xor(c2, m);
    }
    if (l == 0) {
        logits[n * 3 + 0] = c0 + bc[0];
        logits[n * 3 + 1] = c1 + bc[1];
        logits[n * 3 + 2] = c2 + bc[2];
    }
}

extern "C" void kernel_launch(void* const* d_in, const int* in_sizes, int n_in,
                              void* d_out, int out_size, void* d_ws, size_t ws_size,
                              hipStream_t stream) {
    const float* x   = (const float*)d_in[0];
    const int*   ei  = (const int*)d_in[1];
    const float* W1l = (const float*)d_in[2];
    const float* W1r = (const float*)d_in[3];
    const float* b1  = (const float*)d_in[4];
    const float* W2l = (const float*)d_in[5];
    const float* W2r = (const float*)d_in[6];
    const float* b2  = (const float*)d_in[7];
    const float* Wc  = (const float*)d_in[8];
    const float* bc  = (const float*)d_in[9];

    const int* src = ei;
    const int* dst = ei + E_EDGES;

    float* out    = (float*)d_out;
    float* logits = out;
    float* emb    = out + (size_t)N_NODES * 3;

    // ws layout (4B units):
    //   deg_i | offsets | cursor(512) | csr_src (BUCKETS*CAP) | pairs (BUCKETS*CAP)
    //   | r2 (32N fp32) | p8 (8N) | xh (6N: [N][12] halves) | agg1 (12N floats)
    int* ws_i     = (int*)d_ws;
    int* deg_i    = ws_i;
    int* offsets  = ws_i + N_NODES;
    int* cursor   = ws_i + 2 * N_NODES;
    int* csr_src  = cursor + 512;
    int* region1  = csr_src + (size_t)BUCKETS * CAP;
    unsigned int* pairs = (unsigned int*)region1;
    int* base2    = region1 + (size_t)BUCKETS * CAP;
    float* r2     = (float*)base2;                                       // 32N
    unsigned char* p8 = (unsigned char*)(base2 + (size_t)32 * N_NODES);  // 8N units
    __half* xh    = (__half*)(base2 + (size_t)40 * N_NODES);             // 6N units
    float* agg1   = (float*)(base2 + (size_t)46 * N_NODES);              // 12N

    hipMemsetAsync(cursor, 0, 512 * sizeof(int), stream);

    const int BS = 256;

    convert_x_kernel<<<(N_NODES * 12 + BS - 1) / BS, BS, 0, stream>>>(x, xh);
    binA_kernel<<<NWG_A, 1024, 0, stream>>>(src, dst, cursor, pairs);
    binB_kernel<<<BUCKETS, 512, 0, stream>>>(pairs, cursor, deg_i, offsets, csr_src);

    gather1_kernel<<<((size_t)N_NODES * 32 + BS - 1) / BS, BS, 0, stream>>>(
        csr_src, offsets, deg_i, (const __half2*)xh, agg1);
    layer1_proj_kernel<<<(N_NODES + 63) / 64, BS, 0, stream>>>(
        x, agg1, deg_i, W1l, W1r, b1, W2l, W2r, b2, p8, r2);
    layer2_fused_kernel<<<((size_t)N_NODES * 32 + BS - 1) / BS, BS, 0, stream>>>(
        csr_src, offsets, deg_i, (const unsigned int*)p8, r2, Wc, bc, emb, logits);
}

// Round 18
// 221.828 us; speedup vs baseline: 1.0384x; 1.0384x over previous
//
#include <hip/hip_runtime.h>
#include <hip/hip_fp16.h>
#include <hip/hip_fp8.h>

#define N_NODES 100000
#define E_EDGES 3200000
#define F_IN 11
#define F_H 64
#define F_E 32

#define BUCKETS ((N_NODES + 255) >> 8)   // 391 coarse buckets (dst>>8)
#define CAP 9216                         // slack bucket capacity (mean ~8184, +11 sigma)
#define CHUNK_A 12288
#define NWG_A ((E_EDGES + CHUNK_A - 1) / CHUNK_A)  // 261
#define EPT 12                           // binA edges per thread (CHUNK_A / 1024)
#define EPT_B ((CAP + 511) / 512)        // binB pairs per thread (18)

typedef __attribute__((ext_vector_type(8))) _Float16 f16x8;
typedef __attribute__((ext_vector_type(4))) float f32x4;

// ---------------- binA: LDS counting-sort -> coalesced global pair writes ----------
__global__ void binA_kernel(const int* __restrict__ src,
                            const int* __restrict__ dst,
                            int* __restrict__ cursor,
                            unsigned int* __restrict__ pairs) {
    __shared__ int lh[BUCKETS + 1];
    __shared__ int lstart[BUCKETS + 1];
    __shared__ int lcur[BUCKETS];
    __shared__ int gbase[BUCKETS];
    __shared__ unsigned int stage[CHUNK_A];
    int t = threadIdx.x;
    for (int i = t; i <= BUCKETS; i += 1024) lh[i] = 0;
    __syncthreads();

    int e0 = blockIdx.x * CHUNK_A;
    int e1 = min(e0 + CHUNK_A, E_EDGES);

    unsigned int pv[EPT];
    int pb[EPT];
    int cnt = 0;
    for (int i = e0 + t; i < e1; i += 1024) {
        int d = dst[i];
        int b = d >> 8;
        pv[cnt] = (unsigned int)src[i] | (((unsigned int)(d & 255)) << 17);
        pb[cnt] = b;
        ++cnt;
        atomicAdd(&lh[b], 1);
    }
    __syncthreads();

    for (int i = t; i < BUCKETS; i += 1024) lstart[i] = lh[i];
    __syncthreads();
    for (int off = 1; off < 512; off <<= 1) {
        int v = 0;
        if (t < BUCKETS && t >= off) v = lstart[t - off];
        __syncthreads();
        if (t < BUCKETS && t >= off) lstart[t] += v;
        __syncthreads();
    }
    int myIncl = (t < BUCKETS) ? lstart[t] : 0;
    int myCnt  = (t < BUCKETS) ? lh[t] : 0;
    __syncthreads();
    if (t < BUCKETS) {
        int ex = myIncl - myCnt;
        lstart[t] = ex;
        lcur[t] = ex;
        if (myCnt > 0) gbase[t] = t * CAP + atomicAdd(&cursor[t], myCnt);
    }
    if (t == 0) lstart[BUCKETS] = e1 - e0;
    __syncthreads();

    for (int k = 0; k < cnt; ++k) {
        int pos = atomicAdd(&lcur[pb[k]], 1);
        stage[pos] = pv[k];
    }
    __syncthreads();

    int total = e1 - e0;
    for (int i = t; i < total; i += 1024) {
        int lo = 0, hi = BUCKETS;
        while (hi - lo > 1) {
            int mid = (lo + hi) >> 1;
            if (lstart[mid] <= i) lo = mid; else hi = mid;
        }
        pairs[gbase[lo] + (i - lstart[lo])] = stage[i];
    }
}

// ---------------- binB: single pairs read, LDS sort, coalesced csr write ----------
__global__ __launch_bounds__(512) void binB_kernel(const unsigned int* __restrict__ pairs,
                                                   const int* __restrict__ cursor,
                                                   int* __restrict__ deg_i,
                                                   int* __restrict__ offsets,
                                                   int* __restrict__ csr_src) {
    __shared__ int lhist[256];
    __shared__ int lscan[256];
    __shared__ int lcur[256];
    __shared__ unsigned int stage[CAP];
    int b = blockIdx.x;
    int t = threadIdx.x;
    if (t < 256) lhist[t] = 0;
    __syncthreads();
    int start = b * CAP;
    int cntAll = cursor[b];
    unsigned int pv[EPT_B];
    int c = 0;
    for (int i = t; i < cntAll; i += 512) {
        unsigned int p = pairs[start + i];
        pv[c++] = p;
        atomicAdd(&lhist[p >> 17], 1);
    }
    __syncthreads();
    int cnt = (t < 256) ? lhist[t] : 0;
    if (t < 256) lscan[t] = cnt;
    __syncthreads();
    int incl = cnt;
    for (int off = 1; off < 256; off <<= 1) {
        int tmp = (t < 256 && t >= off) ? lscan[t - off] : 0;
        __syncthreads();
        if (t < 256) {
            incl += tmp;
            lscan[t] = incl;
        }
        __syncthreads();
    }
    if (t < 256) {
        int ex = incl - cnt;
        int node = (b << 8) + t;
        if (node < N_NODES) {
            deg_i[node] = cnt;
            offsets[node] = start + ex;
        }
        lcur[t] = ex;
    }
    __syncthreads();
    for (int k = 0; k < c; ++k) {
        int pos = atomicAdd(&lcur[pv[k] >> 17], 1);
        stage[pos] = pv[k] & 0x1FFFFu;
    }
    __syncthreads();
    for (int i = t; i < cntAll; i += 512)
        csr_src[start + i] = (int)stage[i];
}

// ---------------- fp16 conversion of x: [N][12] halves (24B rows) ----------------
__global__ void convert_x_kernel(const float* __restrict__ x, __half* __restrict__ xh) {
    int tid = blockIdx.x * blockDim.x + threadIdx.x;
    if (tid >= N_NODES * 12) return;
    int n = tid / 12;
    int f = tid - n * 12;
    xh[tid] = __float2half((f < F_IN) ? x[n * F_IN + f] : 0.0f);
}

// ---------------- layer 1 gather: 16 lanes/node (8 feat-lanes x 2 deg-halves) -------
__global__ void gather1_kernel(const int* __restrict__ csr_src,
                               const int* __restrict__ offsets,
                               const int* __restrict__ deg_i,
                               const __half2* __restrict__ xh2,
                               float* __restrict__ agg1) {
    int tid = blockIdx.x * blockDim.x + threadIdx.x;
    int n = tid >> 4;
    int lane16 = tid & 15;
    int f2 = lane16 & 7;
    int half = lane16 >> 3;
    if (n >= N_NODES) return;
    int start = offsets[n];
    int cnt = deg_i[n];
    int mid = start + (cnt >> 1);
    int end = start + cnt;
    int i0 = half ? mid : start;
    int i1 = half ? end : mid;
    float2 r = {0.f, 0.f};
    if (f2 < 6) {
        float2 a0 = {0,0}, a1 = {0,0}, a2 = {0,0}, a3 = {0,0};
        int i = i0;
        for (; i + 4 <= i1; i += 4) {
            int s0 = csr_src[i], s1 = csr_src[i + 1], s2 = csr_src[i + 2], s3 = csr_src[i + 3];
            float2 v0 = __half22float2(xh2[s0 * 6 + f2]);
            float2 v1 = __half22float2(xh2[s1 * 6 + f2]);
            float2 v2 = __half22float2(xh2[s2 * 6 + f2]);
            float2 v3 = __half22float2(xh2[s3 * 6 + f2]);
            a0.x += v0.x; a0.y += v0.y;
            a1.x += v1.x; a1.y += v1.y;
            a2.x += v2.x; a2.y += v2.y;
            a3.x += v3.x; a3.y += v3.y;
        }
        for (; i < i1; ++i) {
            float2 v = __half22float2(xh2[csr_src[i] * 6 + f2]);
            a0.x += v.x; a0.y += v.y;
        }
        r.x = a0.x + a1.x + a2.x + a3.x;
        r.y = a0.y + a1.y + a2.y + a3.y;
    }
    r.x += __shfl_xor(r.x, 8);
    r.y += __shfl_xor(r.y, 8);
    if (half == 0 && f2 < 6)
        ((float2*)agg1)[n * 6 + f2] = r;
}

// ---------------- fused layer1 + dual projection via MFMA ----------------
__global__ __launch_bounds__(256) void layer1_proj_kernel(
        const float* __restrict__ x,
        const float* __restrict__ agg1,
        const int* __restrict__ deg_i,
        const float* __restrict__ W1l,
        const float* __restrict__ W1r,
        const float* __restrict__ b1,
        const float* __restrict__ W2l,
        const float* __restrict__ W2r,
        const float* __restrict__ b2,
        unsigned char* __restrict__ p8,
        float* __restrict__ r2) {
    __shared__ __attribute__((aligned(16))) _Float16 hA1[64][32];
    __shared__ __attribute__((aligned(16))) _Float16 WB1[64][32];
    __shared__ __attribute__((aligned(16))) _Float16 WB2[64][64];
    __shared__ __attribute__((aligned(16))) _Float16 hS[64][64];
    int t = threadIdx.x;
    int n0 = blockIdx.x * 64;

    for (int i = t; i < 64 * 32; i += 256) {
        int n = i >> 5, k = i & 31;
        float v = 0.0f;
        if (k < F_IN) v = W1l[k * F_H + n];
        else if (k < 2 * F_IN) v = W1r[(k - F_IN) * F_H + n];
        WB1[n][k] = (_Float16)v;
    }
    for (int i = t; i < 64 * 64; i += 256) {
        int n = i >> 6, k = i & 63;
        float v = (n < F_E) ? W2l[k * F_E + n] : W2r[k * F_E + (n - F_E)];
        WB2[n][k] = (_Float16)v;
    }
    for (int i = t; i < 64 * 32; i += 256) {
        int nl = i >> 5, k = i & 31;
        int n = n0 + nl;
        if (n >= N_NODES) n = N_NODES - 1;
        float v = 0.0f;
        if (k < F_IN) {
            float invd = 1.0f / fmaxf((float)deg_i[n], 1.0f);
            v = agg1[n * 12 + k] * invd;
        } else if (k < 2 * F_IN) {
            v = x[n * F_IN + (k - F_IN)];
        }
        hA1[nl][k] = (_Float16)v;
    }
    __syncthreads();

    int lane = t & 63;
    int wave = t >> 6;
    int col = lane & 15;
    int quad = lane >> 4;
    int mbase = wave * 16;

    f16x8 afrag = *(const f16x8*)&hA1[mbase + col][quad * 8];
    #pragma unroll
    for (int nt = 0; nt < 4; ++nt) {
        f16x8 bfrag = *(const f16x8*)&WB1[nt * 16 + col][quad * 8];
        float bias = b1[nt * 16 + col];
        f32x4 acc = {bias, bias, bias, bias};
        acc = __builtin_amdgcn_mfma_f32_16x16x32_f16(afrag, bfrag, acc, 0, 0, 0);
        #pragma unroll
        for (int r = 0; r < 4; ++r)
            hS[mbase + quad * 4 + r][nt * 16 + col] = (_Float16)fmaxf(acc[r], 0.0f);
    }
    __syncthreads();

    f16x8 a0 = *(const f16x8*)&hS[mbase + col][quad * 8];
    f16x8 a1 = *(const f16x8*)&hS[mbase + col][32 + quad * 8];
    #pragma unroll
    for (int nt = 0; nt < 4; ++nt) {
        f16x8 bf0 = *(const f16x8*)&WB2[nt * 16 + col][quad * 8];
        f16x8 bf1 = *(const f16x8*)&WB2[nt * 16 + col][32 + quad * 8];
        f32x4 acc;
        if (nt < 2) {
            acc = (f32x4){0.f, 0.f, 0.f, 0.f};
        } else {
            float bb = b2[(nt - 2) * 16 + col];
            acc = (f32x4){bb, bb, bb, bb};
        }
        acc = __builtin_amdgcn_mfma_f32_16x16x32_f16(a0, bf0, acc, 0, 0, 0);
        acc = __builtin_amdgcn_mfma_f32_16x16x32_f16(a1, bf1, acc, 0, 0, 0);
        #pragma unroll
        for (int r = 0; r < 4; ++r) {
            int node = n0 + mbase + quad * 4 + r;
            if (node < N_NODES) {
                if (nt < 2) {
                    __hip_fp8_e4m3 q((float)acc[r]);
                    p8[(size_t)node * F_E + nt * 16 + col] = (unsigned char)q.__x;
                } else {
                    r2[(size_t)node * F_E + (nt - 2) * 16 + col] = acc[r];
                }
            }
        }
    }
}

// decode 4 packed fp8 e4m3 -> 4 floats
__device__ inline float4 fp8x4_to_f32(unsigned int w) {
    __hip_fp8_e4m3 a, b, c, d;
    a.__x = (__hip_fp8_storage_t)(w & 0xFF);
    b.__x = (__hip_fp8_storage_t)((w >> 8) & 0xFF);
    c.__x = (__hip_fp8_storage_t)((w >> 16) & 0xFF);
    d.__x = (__hip_fp8_storage_t)((w >> 24) & 0xFF);
    return make_float4((float)a, (float)b, (float)c, (float)d);
}

// ---------------- layer 2 fused: 16 lanes/node (8 feat-lanes x 2 deg-halves) --------
__global__ void layer2_fused_kernel(const int* __restrict__ csr_src,
                                    const int* __restrict__ offsets,
                                    const int* __restrict__ deg_i,
                                    const unsigned int* __restrict__ p8u,  // [N][8] uint
                                    const float* __restrict__ r2,
                                    const float* __restrict__ Wc,
                                    const float* __restrict__ bc,
                                    float* __restrict__ emb,
                                    float* __restrict__ logits) {
    int tid = blockIdx.x * blockDim.x + threadIdx.x;
    int n = tid >> 4;
    int lane16 = tid & 15;
    int l = lane16 & 7;
    int half = lane16 >> 3;
    if (n >= N_NODES) return;
    int start = offsets[n];
    int cnt = deg_i[n];
    int mid = start + (cnt >> 1);
    int end = start + cnt;
    int i0 = half ? mid : start;
    int i1 = half ? end : mid;
    float ax = 0.f, ay = 0.f, az = 0.f, aw = 0.f;
    float bx = 0.f, by = 0.f, bz = 0.f, bw = 0.f;
    int i = i0;
    for (; i + 4 <= i1; i += 4) {
        int s0 = csr_src[i], s1 = csr_src[i + 1], s2 = csr_src[i + 2], s3 = csr_src[i + 3];
        unsigned int w0 = p8u[s0 * 8 + l];
        unsigned int w1 = p8u[s1 * 8 + l];
        unsigned int w2 = p8u[s2 * 8 + l];
        unsigned int w3 = p8u[s3 * 8 + l];
        float4 v0 = fp8x4_to_f32(w0);
        float4 v1 = fp8x4_to_f32(w1);
        float4 v2 = fp8x4_to_f32(w2);
        float4 v3 = fp8x4_to_f32(w3);
        ax += v0.x + v2.x; ay += v0.y + v2.y; az += v0.z + v2.z; aw += v0.w + v2.w;
        bx += v1.x + v3.x; by += v1.y + v3.y; bz += v1.z + v3.z; bw += v1.w + v3.w;
    }
    for (; i < i1; ++i) {
        float4 v = fp8x4_to_f32(p8u[csr_src[i] * 8 + l]);
        ax += v.x; ay += v.y; az += v.z; aw += v.w;
    }
    float sx = ax + bx, sy = ay + by, sz = az + bz, sw = aw + bw;
    sx += __shfl_xor(sx, 8);
    sy += __shfl_xor(sy, 8);
    sz += __shfl_xor(sz, 8);
    sw += __shfl_xor(sw, 8);
    float invd = 1.0f / fmaxf((float)cnt, 1.0f);
    const float* rrow = r2 + n * F_E + 4 * l;
    float4 e;
    e.x = fmaxf(sx * invd + rrow[0], 0.0f);
    e.y = fmaxf(sy * invd + rrow[1], 0.0f);
    e.z = fmaxf(sz * invd + rrow[2], 0.0f);
    e.w = fmaxf(sw * invd + rrow[3], 0.0f);
    if (half == 0)
        ((float4*)emb)[n * 8 + l] = e;
    const float* wc = Wc + (4 * l) * 3;
    float c0 = e.x * wc[0] + e.y * wc[3] + e.z * wc[6] + e.w * wc[9];
    float c1 = e.x * wc[1] + e.y * wc[4] + e.z * wc[7] + e.w * wc[10];
    float c2 = e.x * wc[2] + e.y * wc[5] + e.z * wc[8] + e.w * wc[11];
    #pragma unroll
    for (int m = 1; m < 8; m <<= 1) {
        c0 += __shfl_xor(c0, m);
        c1 += __shfl_xor(c1, m);
        c2 += __shfl_xor(c2, m);
    }
    if (lane16 == 0) {
        logits[n * 3 + 0] = c0 + bc[0];
        logits[n * 3 + 1] = c1 + bc[1];
        logits[n * 3 + 2] = c2 + bc[2];
    }
}

extern "C" void kernel_launch(void* const* d_in, const int* in_sizes, int n_in,
                              void* d_out, int out_size, void* d_ws, size_t ws_size,
                              hipStream_t stream) {
    const float* x   = (const float*)d_in[0];
    const int*   ei  = (const int*)d_in[1];
    const float* W1l = (const float*)d_in[2];
    const float* W1r = (const float*)d_in[3];
    const float* b1  = (const float*)d_in[4];
    const float* W2l = (const float*)d_in[5];
    const float* W2r = (const float*)d_in[6];
    const float* b2  = (const float*)d_in[7];
    const float* Wc  = (const float*)d_in[8];
    const float* bc  = (const float*)d_in[9];

    const int* src = ei;
    const int* dst = ei + E_EDGES;

    float* out    = (float*)d_out;
    float* logits = out;
    float* emb    = out + (size_t)N_NODES * 3;

    // ws layout (4B units):
    //   deg_i | offsets | cursor(512) | csr_src (BUCKETS*CAP) | pairs (BUCKETS*CAP)
    //   | r2 (32N fp32) | p8 (8N) | xh (6N: [N][12] halves) | agg1 (12N floats)
    int* ws_i     = (int*)d_ws;
    int* deg_i    = ws_i;
    int* offsets  = ws_i + N_NODES;
    int* cursor   = ws_i + 2 * N_NODES;
    int* csr_src  = cursor + 512;
    int* region1  = csr_src + (size_t)BUCKETS * CAP;
    unsigned int* pairs = (unsigned int*)region1;
    int* base2    = region1 + (size_t)BUCKETS * CAP;
    float* r2     = (float*)base2;                                       // 32N
    unsigned char* p8 = (unsigned char*)(base2 + (size_t)32 * N_NODES);  // 8N units
    __half* xh    = (__half*)(base2 + (size_t)40 * N_NODES);             // 6N units
    float* agg1   = (float*)(base2 + (size_t)46 * N_NODES);              // 12N

    hipMemsetAsync(cursor, 0, 512 * sizeof(int), stream);

    const int BS = 256;

    convert_x_kernel<<<(N_NODES * 12 + BS - 1) / BS, BS, 0, stream>>>(x, xh);
    binA_kernel<<<NWG_A, 1024, 0, stream>>>(src, dst, cursor, pairs);
    binB_kernel<<<BUCKETS, 512, 0, stream>>>(pairs, cursor, deg_i, offsets, csr_src);

    gather1_kernel<<<(N_NODES * 16 + BS - 1) / BS, BS, 0, stream>>>(
        csr_src, offsets, deg_i, (const __half2*)xh, agg1);
    layer1_proj_kernel<<<(N_NODES + 63) / 64, BS, 0, stream>>>(
        x, agg1, deg_i, W1l, W1r, b1, W2l, W2r, b2, p8, r2);
    layer2_fused_kernel<<<(N_NODES * 16 + BS - 1) / BS, BS, 0, stream>>>(
        csr_src, offsets, deg_i, (const unsigned int*)p8, r2, Wc, bc, emb, logits);
}